// Round 3
// baseline (967.581 us; speedup 1.0000x reference)
//
#include <hip/hip_runtime.h>

#define NNODES 50000
#define NEDGES 500000
#define DIN 128
#define DHID 256

typedef unsigned short u16;
typedef __attribute__((ext_vector_type(8))) short short8;
typedef __attribute__((ext_vector_type(4))) float f32x4;

__device__ __forceinline__ float bf2f(unsigned int u) {
  union { unsigned int i; float f; } v; v.i = u << 16; return v.f;
}
__device__ __forceinline__ u16 f2bf(float f) {
  union { unsigned int i; float f; } v; v.f = f;
  unsigned int x = v.i;
  x += 0x7fffu + ((x >> 16) & 1u);   // RNE
  return (u16)(x >> 16);
}
__device__ __forceinline__ void split_bf(float x, u16& hi, u16& lo) {
  hi = f2bf(x);
  lo = f2bf(x - bf2f(hi));
}

__global__ void k_zero_i32(int* __restrict__ p, int n) {
  int i = blockIdx.x * blockDim.x + threadIdx.x;
  if (i < n) p[i] = 0;
}

__global__ void k_hist(const int* __restrict__ dst, int* __restrict__ deg, int e) {
  int i = blockIdx.x * blockDim.x + threadIdx.x;
  if (i < e) atomicAdd(&deg[dst[i]], 1);
}

__global__ void k_dinv(const int* __restrict__ deg, float* __restrict__ dinv, int n) {
  int i = blockIdx.x * blockDim.x + threadIdx.x;
  if (i < n) dinv[i] = rsqrtf((float)deg[i] + 1.0f);  // +1 = self loop
}

// exclusive scan of deg[0..n) -> row_ptr[0..n], single workgroup
__global__ __launch_bounds__(1024) void k_scan(const int* __restrict__ deg,
                                               int* __restrict__ row_ptr, int n) {
  __shared__ int part[1024];
  const int t = threadIdx.x;
  const int C = (n + 1023) >> 10;
  const int base = t * C;
  int sum = 0;
  for (int j = 0; j < C; ++j) {
    int idx = base + j;
    if (idx < n) sum += deg[idx];
  }
  part[t] = sum;
  __syncthreads();
  for (int off = 1; off < 1024; off <<= 1) {
    int v = (t >= off) ? part[t - off] : 0;
    __syncthreads();
    part[t] += v;
    __syncthreads();
  }
  int run = (t == 0) ? 0 : part[t - 1];
  for (int j = 0; j < C; ++j) {
    int idx = base + j;
    if (idx < n) { row_ptr[idx] = run; run += deg[idx]; }
  }
  if (t == 1023) row_ptr[n] = part[1023];
}

__global__ void k_fill(const int* __restrict__ src, const int* __restrict__ dst,
                       const int* __restrict__ row_ptr, int* __restrict__ cursor,
                       int* __restrict__ csr_src, int e) {
  int i = blockIdx.x * blockDim.x + threadIdx.x;
  if (i < e) {
    int d = dst[i];
    int pos = row_ptr[d] + atomicAdd(&cursor[d], 1);
    csr_src[pos] = src[i];
  }
}

// x [M,K] f32 -> hi/lo bf16 row-major
__global__ void k_split_x(const float* __restrict__ x, u16* __restrict__ hi,
                          u16* __restrict__ lo, int total4) {
  int i = blockIdx.x * blockDim.x + threadIdx.x;
  if (i >= total4) return;
  float4 v = *(const float4*)(x + (size_t)i * 4);
  ushort4 h, l;
  split_bf(v.x, h.x, l.x);
  split_bf(v.y, h.y, l.y);
  split_bf(v.z, h.z, l.z);
  split_bf(v.w, h.w, l.w);
  *(ushort4*)(hi + (size_t)i * 4) = h;
  *(ushort4*)(lo + (size_t)i * 4) = l;
}

// W [K,256] f32 -> swizzled bf16 hi/lo in B-fragment order:
// frag for (k-tile t, col-tile c), lane L holds B[k=t*32+(L>>4)*8+j][n=c*16+(L&15)]
// stored at ((t*16+c)*64 + L)*8 + j
__global__ void k_splitW(const float* __restrict__ W, u16* __restrict__ hi,
                         u16* __restrict__ lo, int total) {
  int i = blockIdx.x * blockDim.x + threadIdx.x;
  if (i >= total) return;
  int k = i >> 8, n = i & 255;
  int t = k >> 5, q = (k >> 3) & 3, j = k & 7;
  int c = n >> 4, m = n & 15;
  size_t pos = (((size_t)(t * 16 + c)) * 64 + q * 16 + m) * 8 + j;
  u16 h, l;
  split_bf(W[i], h, l);
  hi[pos] = h;
  lo[pos] = l;
}

// C[M,256] = (Ahi+Alo)[M,K] @ (Bhi+Blo)[K,256] via 3-pass split-bf16 MFMA.
// 1 wave = 16 rows x 256 cols; block = 4 waves = 64 rows. No LDS.
template<int K>
__global__ __launch_bounds__(256) void k_gemm_mfma(const u16* __restrict__ Ahi,
                                                   const u16* __restrict__ Alo,
                                                   const u16* __restrict__ Bhi,
                                                   const u16* __restrict__ Blo,
                                                   float* __restrict__ C, int M) {
  const int lane = threadIdx.x & 63;
  const int wave = threadIdx.x >> 6;
  const int m0 = blockIdx.x * 64 + wave * 16;
  if (m0 >= M) return;

  f32x4 acc[16];
#pragma unroll
  for (int c = 0; c < 16; ++c) acc[c] = {0.f, 0.f, 0.f, 0.f};

  const u16* ah_p = Ahi + (size_t)(m0 + (lane & 15)) * K + ((lane >> 4) * 8);
  const u16* al_p = Alo + (size_t)(m0 + (lane & 15)) * K + ((lane >> 4) * 8);

#pragma unroll
  for (int t = 0; t < K / 32; ++t) {
    short8 ah = *(const short8*)(ah_p + t * 32);
    short8 al = *(const short8*)(al_p + t * 32);
#pragma unroll 4
    for (int c = 0; c < 16; ++c) {
      size_t boff = (((size_t)(t * 16 + c)) * 64 + lane) * 8;
      short8 bh = *(const short8*)(Bhi + boff);
      short8 bl = *(const short8*)(Blo + boff);
      acc[c] = __builtin_amdgcn_mfma_f32_16x16x32_bf16(ah, bh, acc[c], 0, 0, 0);
      acc[c] = __builtin_amdgcn_mfma_f32_16x16x32_bf16(al, bh, acc[c], 0, 0, 0);
      acc[c] = __builtin_amdgcn_mfma_f32_16x16x32_bf16(ah, bl, acc[c], 0, 0, 0);
    }
  }

  const int rbase = m0 + ((lane >> 4) * 4);
  const int cbase = lane & 15;
#pragma unroll
  for (int c = 0; c < 16; ++c) {
#pragma unroll
    for (int r = 0; r < 4; ++r) {
      C[(size_t)(rbase + r) * 256 + c * 16 + cbase] = acc[c][r];
    }
  }
}

// one wave per node; 64 lanes x float4 = 256 channels
// MODE 0: relu + split-bf16 output (hhi/hlo); MODE 1: plain f32 output (final)
template<int MODE>
__global__ __launch_bounds__(256) void k_agg(const float* __restrict__ h,
                                             const float* __restrict__ dinv,
                                             const int* __restrict__ row_ptr,
                                             const int* __restrict__ csr_src,
                                             const float* __restrict__ bias,
                                             u16* __restrict__ hhi,
                                             u16* __restrict__ hlo,
                                             float* __restrict__ out, int n) {
  int node = blockIdx.x * 4 + (threadIdx.x >> 6);
  if (node >= n) return;
  int lane = threadIdx.x & 63;
  int c = lane * 4;
  float di = dinv[node];
  float s2 = di * di;
  float4 hv = *(const float4*)(h + (size_t)node * 256 + c);
  float4 bv = *(const float4*)(bias + c);
  float4 acc;
  acc.x = fmaf(s2, hv.x, bv.x);
  acc.y = fmaf(s2, hv.y, bv.y);
  acc.z = fmaf(s2, hv.z, bv.z);
  acc.w = fmaf(s2, hv.w, bv.w);
  int p0 = row_ptr[node], p1 = row_ptr[node + 1];
  for (int p = p0; p < p1; ++p) {
    int s = csr_src[p];
    float w = dinv[s] * di;
    float4 v = *(const float4*)(h + (size_t)s * 256 + c);
    acc.x = fmaf(w, v.x, acc.x);
    acc.y = fmaf(w, v.y, acc.y);
    acc.z = fmaf(w, v.z, acc.z);
    acc.w = fmaf(w, v.w, acc.w);
  }
  if (MODE == 0) {
    acc.x = fmaxf(acc.x, 0.f); acc.y = fmaxf(acc.y, 0.f);
    acc.z = fmaxf(acc.z, 0.f); acc.w = fmaxf(acc.w, 0.f);
    ushort4 hq, lq;
    split_bf(acc.x, hq.x, lq.x);
    split_bf(acc.y, hq.y, lq.y);
    split_bf(acc.z, hq.z, lq.z);
    split_bf(acc.w, hq.w, lq.w);
    *(ushort4*)(hhi + (size_t)node * 256 + c) = hq;
    *(ushort4*)(hlo + (size_t)node * 256 + c) = lq;
  } else {
    *(float4*)(out + (size_t)node * 256 + c) = acc;
  }
}

extern "C" void kernel_launch(void* const* d_in, const int* in_sizes, int n_in,
                              void* d_out, int out_size, void* d_ws, size_t ws_size,
                              hipStream_t stream) {
  const float* x  = (const float*)d_in[0];
  const int*   ei = (const int*)d_in[1];
  const float* W1 = (const float*)d_in[2];
  const float* b1 = (const float*)d_in[3];
  const float* W2 = (const float*)d_in[4];
  const float* b2 = (const float*)d_in[5];
  const float* W3 = (const float*)d_in[6];
  const float* b3 = (const float*)d_in[7];
  float* out = (float*)d_out;
  (void)in_sizes; (void)n_in; (void)out_size; (void)ws_size;

  char* ws = (char*)d_ws;
  size_t off = 0;
  auto alloc = [&](size_t bytes) -> void* {
    void* p = (void*)(ws + off);
    off += (bytes + 255) & ~(size_t)255;
    return p;
  };
  float* dinv    = (float*)alloc((size_t)NNODES * 4);
  int*   deg     = (int*)alloc((size_t)NNODES * 4);
  int*   row_ptr = (int*)alloc((size_t)(NNODES + 1) * 4);
  int*   csr_src = (int*)alloc((size_t)NEDGES * 4);
  float* bufA    = (float*)alloc((size_t)NNODES * 256 * 4);   // gemm out / agg in
  u16*   Hhi     = (u16*)alloc((size_t)NNODES * 256 * 2);     // also holds Xhi (K=128)
  u16*   Hlo     = (u16*)alloc((size_t)NNODES * 256 * 2);     // also holds Xlo
  u16*   W1hi    = (u16*)alloc((size_t)DIN * 256 * 2);
  u16*   W1lo    = (u16*)alloc((size_t)DIN * 256 * 2);
  u16*   W2hi    = (u16*)alloc((size_t)DHID * 256 * 2);
  u16*   W2lo    = (u16*)alloc((size_t)DHID * 256 * 2);
  u16*   W3hi    = (u16*)alloc((size_t)DHID * 256 * 2);
  u16*   W3lo    = (u16*)alloc((size_t)DHID * 256 * 2);

  const int* e_src = ei;
  const int* e_dst = ei + NEDGES;

  const int tb = 256;
  k_zero_i32<<<(NNODES + tb - 1) / tb, tb, 0, stream>>>(deg, NNODES);
  k_hist<<<(NEDGES + tb - 1) / tb, tb, 0, stream>>>(e_dst, deg, NEDGES);
  k_dinv<<<(NNODES + tb - 1) / tb, tb, 0, stream>>>(deg, dinv, NNODES);
  k_scan<<<1, 1024, 0, stream>>>(deg, row_ptr, NNODES);
  k_zero_i32<<<(NNODES + tb - 1) / tb, tb, 0, stream>>>(deg, NNODES);
  k_fill<<<(NEDGES + tb - 1) / tb, tb, 0, stream>>>(e_src, e_dst, row_ptr, deg,
                                                    csr_src, NEDGES);

  // input split + weight swizzle/split
  int x4 = NNODES * DIN / 4;
  k_split_x<<<(x4 + tb - 1) / tb, tb, 0, stream>>>(x, Hhi, Hlo, x4);
  k_splitW<<<(DIN * 256 + tb - 1) / tb, tb, 0, stream>>>(W1, W1hi, W1lo, DIN * 256);
  k_splitW<<<(DHID * 256 + tb - 1) / tb, tb, 0, stream>>>(W2, W2hi, W2lo, DHID * 256);
  k_splitW<<<(DHID * 256 + tb - 1) / tb, tb, 0, stream>>>(W3, W3hi, W3lo, DHID * 256);

  const int gblocks = (NNODES / 16 + 3) / 4;  // 3125 row-tiles / 4 waves
  const int ablocks = (NNODES + 3) / 4;

  k_gemm_mfma<DIN><<<gblocks, 256, 0, stream>>>(Hhi, Hlo, W1hi, W1lo, bufA, NNODES);
  k_agg<0><<<ablocks, 256, 0, stream>>>(bufA, dinv, row_ptr, csr_src, b1,
                                        Hhi, Hlo, nullptr, NNODES);
  k_gemm_mfma<DHID><<<gblocks, 256, 0, stream>>>(Hhi, Hlo, W2hi, W2lo, bufA, NNODES);
  k_agg<0><<<ablocks, 256, 0, stream>>>(bufA, dinv, row_ptr, csr_src, b2,
                                        Hhi, Hlo, nullptr, NNODES);
  k_gemm_mfma<DHID><<<gblocks, 256, 0, stream>>>(Hhi, Hlo, W3hi, W3lo, bufA, NNODES);
  k_agg<1><<<ablocks, 256, 0, stream>>>(bufA, dinv, row_ptr, csr_src, b3,
                                        nullptr, nullptr, out, NNODES);
}

// Round 4
// 614.310 us; speedup vs baseline: 1.5751x; 1.5751x over previous
//
#include <hip/hip_runtime.h>

#define NNODES 50000
#define NEDGES 500000
#define DIN 128
#define DHID 256
#define MPAD 50048   // 391 blocks * 128 rows

typedef unsigned short u16;
typedef __attribute__((ext_vector_type(8))) short short8;
typedef __attribute__((ext_vector_type(4))) float f32x4;

__device__ __forceinline__ float bf2f(unsigned int u) {
  union { unsigned int i; float f; } v; v.i = u << 16; return v.f;
}
__device__ __forceinline__ u16 f2bf(float f) {
  union { unsigned int i; float f; } v; v.f = f;
  unsigned int x = v.i;
  x += 0x7fffu + ((x >> 16) & 1u);   // RNE
  return (u16)(x >> 16);
}
__device__ __forceinline__ void split_bf(float x, u16& hi, u16& lo) {
  hi = f2bf(x);
  lo = f2bf(x - bf2f(hi));
}

__global__ void k_zero_i32(int* __restrict__ p, int n) {
  int i = blockIdx.x * blockDim.x + threadIdx.x;
  if (i < n) p[i] = 0;
}

__global__ void k_hist(const int* __restrict__ dst, int* __restrict__ deg, int e) {
  int i = blockIdx.x * blockDim.x + threadIdx.x;
  if (i < e) atomicAdd(&deg[dst[i]], 1);
}

__global__ void k_dinv(const int* __restrict__ deg, float* __restrict__ dinv, int n) {
  int i = blockIdx.x * blockDim.x + threadIdx.x;
  if (i < n) dinv[i] = rsqrtf((float)deg[i] + 1.0f);  // +1 = self loop
}

// exclusive scan of deg[0..n) -> row_ptr[0..n], single workgroup
__global__ __launch_bounds__(1024) void k_scan(const int* __restrict__ deg,
                                               int* __restrict__ row_ptr, int n) {
  __shared__ int part[1024];
  const int t = threadIdx.x;
  const int C = (n + 1023) >> 10;
  const int base = t * C;
  int sum = 0;
  for (int j = 0; j < C; ++j) {
    int idx = base + j;
    if (idx < n) sum += deg[idx];
  }
  part[t] = sum;
  __syncthreads();
  for (int off = 1; off < 1024; off <<= 1) {
    int v = (t >= off) ? part[t - off] : 0;
    __syncthreads();
    part[t] += v;
    __syncthreads();
  }
  int run = (t == 0) ? 0 : part[t - 1];
  for (int j = 0; j < C; ++j) {
    int idx = base + j;
    if (idx < n) { row_ptr[idx] = run; run += deg[idx]; }
  }
  if (t == 1023) row_ptr[n] = part[1023];
}

__global__ void k_fill(const int* __restrict__ src, const int* __restrict__ dst,
                       const int* __restrict__ row_ptr, int* __restrict__ cursor,
                       int* __restrict__ csr_src, int e) {
  int i = blockIdx.x * blockDim.x + threadIdx.x;
  if (i < e) {
    int d = dst[i];
    int pos = row_ptr[d] + atomicAdd(&cursor[d], 1);
    csr_src[pos] = src[i];
  }
}

// x [M,K] f32 -> hi/lo bf16 row-major
__global__ void k_split_x(const float* __restrict__ x, u16* __restrict__ hi,
                          u16* __restrict__ lo, int total4) {
  int i = blockIdx.x * blockDim.x + threadIdx.x;
  if (i >= total4) return;
  float4 v = *(const float4*)(x + (size_t)i * 4);
  ushort4 h, l;
  split_bf(v.x, h.x, l.x);
  split_bf(v.y, h.y, l.y);
  split_bf(v.z, h.z, l.z);
  split_bf(v.w, h.w, l.w);
  *(ushort4*)(hi + (size_t)i * 4) = h;
  *(ushort4*)(lo + (size_t)i * 4) = l;
}

// zero pad rows [n0, n1) of hi/lo (row-major, 256 cols)
__global__ void k_zero_pad(u16* __restrict__ hi, u16* __restrict__ lo,
                           int n0, int n1) {
  int i = blockIdx.x * blockDim.x + threadIdx.x;
  int total = (n1 - n0) * 256;
  if (i < total) {
    size_t p = (size_t)n0 * 256 + i;
    hi[p] = 0;
    lo[p] = 0;
  }
}

// W [K,256] f32 -> swizzled bf16 hi/lo in B-fragment order:
// frag (k-tile t, col-tile c): lane L holds B[k=t*32+(L>>4)*8+j][n=c*16+(L&15)]
// at ((t*16+c)*64 + L)*8 + j
__global__ void k_splitW(const float* __restrict__ W, u16* __restrict__ hi,
                         u16* __restrict__ lo, int total) {
  int i = blockIdx.x * blockDim.x + threadIdx.x;
  if (i >= total) return;
  int k = i >> 8, n = i & 255;
  int t = k >> 5, q = (k >> 3) & 3, j = k & 7;
  int c = n >> 4, m = n & 15;
  size_t pos = (((size_t)(t * 16 + c)) * 64 + q * 16 + m) * 8 + j;
  u16 h, l;
  split_bf(W[i], h, l);
  hi[pos] = h;
  lo[pos] = l;
}

// C[Mpad,256] = (Ahi+Alo) @ (Bhi+Blo), 3-pass split-bf16 MFMA.
// 1 wave = 32 rows (2 row-frags) x 256 cols; block = 4 waves = 128 rows. No LDS.
// A is padded to MPAD rows (pad rows zero), so no masking anywhere.
template<int K>
__global__ __launch_bounds__(256) void k_gemm_mfma(const u16* __restrict__ Ahi,
                                                   const u16* __restrict__ Alo,
                                                   const u16* __restrict__ Bhi,
                                                   const u16* __restrict__ Blo,
                                                   float* __restrict__ C) {
  const int lane = threadIdx.x & 63;
  const int wave = threadIdx.x >> 6;
  const int m0 = blockIdx.x * 128 + wave * 32;

  f32x4 acc0[16], acc1[16];
#pragma unroll
  for (int c = 0; c < 16; ++c) {
    acc0[c] = {0.f, 0.f, 0.f, 0.f};
    acc1[c] = {0.f, 0.f, 0.f, 0.f};
  }

  const u16* a0h = Ahi + (size_t)(m0 + (lane & 15)) * K + ((lane >> 4) * 8);
  const u16* a0l = Alo + (size_t)(m0 + (lane & 15)) * K + ((lane >> 4) * 8);
  const u16* a1h = a0h + (size_t)16 * K;
  const u16* a1l = a0l + (size_t)16 * K;

  for (int t = 0; t < K / 32; ++t) {
    short8 ah0 = *(const short8*)(a0h + t * 32);
    short8 al0 = *(const short8*)(a0l + t * 32);
    short8 ah1 = *(const short8*)(a1h + t * 32);
    short8 al1 = *(const short8*)(a1l + t * 32);
    const u16* bbase = Bhi + ((size_t)(t * 16) * 64 + lane) * 8;
    const u16* bbasel = Blo + ((size_t)(t * 16) * 64 + lane) * 8;
#pragma unroll
    for (int c = 0; c < 16; ++c) {
      short8 bh = *(const short8*)(bbase + (size_t)c * 512);
      short8 bl = *(const short8*)(bbasel + (size_t)c * 512);
      acc0[c] = __builtin_amdgcn_mfma_f32_16x16x32_bf16(ah0, bh, acc0[c], 0, 0, 0);
      acc0[c] = __builtin_amdgcn_mfma_f32_16x16x32_bf16(al0, bh, acc0[c], 0, 0, 0);
      acc0[c] = __builtin_amdgcn_mfma_f32_16x16x32_bf16(ah0, bl, acc0[c], 0, 0, 0);
      acc1[c] = __builtin_amdgcn_mfma_f32_16x16x32_bf16(ah1, bh, acc1[c], 0, 0, 0);
      acc1[c] = __builtin_amdgcn_mfma_f32_16x16x32_bf16(al1, bh, acc1[c], 0, 0, 0);
      acc1[c] = __builtin_amdgcn_mfma_f32_16x16x32_bf16(ah1, bl, acc1[c], 0, 0, 0);
    }
  }

  const int rbase = m0 + ((lane >> 4) * 4);
  const int cbase = lane & 15;
#pragma unroll
  for (int c = 0; c < 16; ++c) {
#pragma unroll
    for (int r = 0; r < 4; ++r) {
      C[(size_t)(rbase + r) * 256 + c * 16 + cbase] = acc0[c][r];
      C[(size_t)(rbase + 16 + r) * 256 + c * 16 + cbase] = acc1[c][r];
    }
  }
}

// one wave per node; 64 lanes x float4 = 256 channels
// MODE 0: relu + split-bf16 output (hhi/hlo); MODE 1: plain f32 output (final)
template<int MODE>
__global__ __launch_bounds__(256) void k_agg(const float* __restrict__ h,
                                             const float* __restrict__ dinv,
                                             const int* __restrict__ row_ptr,
                                             const int* __restrict__ csr_src,
                                             const float* __restrict__ bias,
                                             u16* __restrict__ hhi,
                                             u16* __restrict__ hlo,
                                             float* __restrict__ out, int n) {
  int node = blockIdx.x * 4 + (threadIdx.x >> 6);
  if (node >= n) return;
  int lane = threadIdx.x & 63;
  int c = lane * 4;
  float di = dinv[node];
  float s2 = di * di;
  float4 hv = *(const float4*)(h + (size_t)node * 256 + c);
  float4 bv = *(const float4*)(bias + c);
  float4 acc;
  acc.x = fmaf(s2, hv.x, bv.x);
  acc.y = fmaf(s2, hv.y, bv.y);
  acc.z = fmaf(s2, hv.z, bv.z);
  acc.w = fmaf(s2, hv.w, bv.w);
  int p0 = row_ptr[node], p1 = row_ptr[node + 1];
  for (int p = p0; p < p1; ++p) {
    int s = csr_src[p];
    float w = dinv[s] * di;
    float4 v = *(const float4*)(h + (size_t)s * 256 + c);
    acc.x = fmaf(w, v.x, acc.x);
    acc.y = fmaf(w, v.y, acc.y);
    acc.z = fmaf(w, v.z, acc.z);
    acc.w = fmaf(w, v.w, acc.w);
  }
  if (MODE == 0) {
    acc.x = fmaxf(acc.x, 0.f); acc.y = fmaxf(acc.y, 0.f);
    acc.z = fmaxf(acc.z, 0.f); acc.w = fmaxf(acc.w, 0.f);
    ushort4 hq, lq;
    split_bf(acc.x, hq.x, lq.x);
    split_bf(acc.y, hq.y, lq.y);
    split_bf(acc.z, hq.z, lq.z);
    split_bf(acc.w, hq.w, lq.w);
    *(ushort4*)(hhi + (size_t)node * 256 + c) = hq;
    *(ushort4*)(hlo + (size_t)node * 256 + c) = lq;
  } else {
    *(float4*)(out + (size_t)node * 256 + c) = acc;
  }
}

extern "C" void kernel_launch(void* const* d_in, const int* in_sizes, int n_in,
                              void* d_out, int out_size, void* d_ws, size_t ws_size,
                              hipStream_t stream) {
  const float* x  = (const float*)d_in[0];
  const int*   ei = (const int*)d_in[1];
  const float* W1 = (const float*)d_in[2];
  const float* b1 = (const float*)d_in[3];
  const float* W2 = (const float*)d_in[4];
  const float* b2 = (const float*)d_in[5];
  const float* W3 = (const float*)d_in[6];
  const float* b3 = (const float*)d_in[7];
  float* out = (float*)d_out;
  (void)in_sizes; (void)n_in; (void)out_size; (void)ws_size;

  char* ws = (char*)d_ws;
  size_t off = 0;
  auto alloc = [&](size_t bytes) -> void* {
    void* p = (void*)(ws + off);
    off += (bytes + 255) & ~(size_t)255;
    return p;
  };
  float* dinv    = (float*)alloc((size_t)NNODES * 4);
  int*   deg     = (int*)alloc((size_t)NNODES * 4);
  int*   row_ptr = (int*)alloc((size_t)(NNODES + 1) * 4);
  int*   csr_src = (int*)alloc((size_t)NEDGES * 4);
  float* bufA    = (float*)alloc((size_t)MPAD * 256 * 4);   // gemm out / agg in
  u16*   Hhi     = (u16*)alloc((size_t)MPAD * 256 * 2);     // also holds Xhi (K=128)
  u16*   Hlo     = (u16*)alloc((size_t)MPAD * 256 * 2);
  u16*   W1hi    = (u16*)alloc((size_t)DIN * 256 * 2);
  u16*   W1lo    = (u16*)alloc((size_t)DIN * 256 * 2);
  u16*   W2hi    = (u16*)alloc((size_t)DHID * 256 * 2);
  u16*   W2lo    = (u16*)alloc((size_t)DHID * 256 * 2);
  u16*   W3hi    = (u16*)alloc((size_t)DHID * 256 * 2);
  u16*   W3lo    = (u16*)alloc((size_t)DHID * 256 * 2);

  const int* e_src = ei;
  const int* e_dst = ei + NEDGES;

  const int tb = 256;
  k_zero_i32<<<(NNODES + tb - 1) / tb, tb, 0, stream>>>(deg, NNODES);
  k_hist<<<(NEDGES + tb - 1) / tb, tb, 0, stream>>>(e_dst, deg, NEDGES);
  k_dinv<<<(NNODES + tb - 1) / tb, tb, 0, stream>>>(deg, dinv, NNODES);
  k_scan<<<1, 1024, 0, stream>>>(deg, row_ptr, NNODES);
  k_zero_i32<<<(NNODES + tb - 1) / tb, tb, 0, stream>>>(deg, NNODES);
  k_fill<<<(NEDGES + tb - 1) / tb, tb, 0, stream>>>(e_src, e_dst, row_ptr, deg,
                                                    csr_src, NEDGES);

  // input split + pad-zero + weight swizzle/split
  int x4 = NNODES * DIN / 4;
  k_split_x<<<(x4 + tb - 1) / tb, tb, 0, stream>>>(x, Hhi, Hlo, x4);
  int padN = (MPAD - NNODES) * 256;
  k_zero_pad<<<(padN + tb - 1) / tb, tb, 0, stream>>>(Hhi, Hlo, NNODES, MPAD);
  k_splitW<<<(DIN * 256 + tb - 1) / tb, tb, 0, stream>>>(W1, W1hi, W1lo, DIN * 256);
  k_splitW<<<(DHID * 256 + tb - 1) / tb, tb, 0, stream>>>(W2, W2hi, W2lo, DHID * 256);
  k_splitW<<<(DHID * 256 + tb - 1) / tb, tb, 0, stream>>>(W3, W3hi, W3lo, DHID * 256);

  const int gblocks = MPAD / 128;          // 391
  const int ablocks = (NNODES + 3) / 4;

  k_gemm_mfma<DIN><<<gblocks, 256, 0, stream>>>(Hhi, Hlo, W1hi, W1lo, bufA);
  k_agg<0><<<ablocks, 256, 0, stream>>>(bufA, dinv, row_ptr, csr_src, b1,
                                        Hhi, Hlo, nullptr, NNODES);
  k_gemm_mfma<DHID><<<gblocks, 256, 0, stream>>>(Hhi, Hlo, W2hi, W2lo, bufA);
  k_agg<0><<<ablocks, 256, 0, stream>>>(bufA, dinv, row_ptr, csr_src, b2,
                                        Hhi, Hlo, nullptr, NNODES);
  k_gemm_mfma<DHID><<<gblocks, 256, 0, stream>>>(Hhi, Hlo, W3hi, W3lo, bufA);
  k_agg<1><<<ablocks, 256, 0, stream>>>(bufA, dinv, row_ptr, csr_src, b3,
                                        nullptr, nullptr, out, NNODES);
}

// Round 5
// 516.258 us; speedup vs baseline: 1.8742x; 1.1899x over previous
//
#include <hip/hip_runtime.h>

#define NNODES 50000
#define NEDGES 500000
#define DIN 128
#define DHID 256
#define MPAD 50048   // 391 blocks * 128 rows
#define NI4 12500    // NNODES*4/... = 50000 ints / 4 per int4
#define NSB 49       // ceil(12500/256) scan blocks

typedef unsigned short u16;
typedef __attribute__((ext_vector_type(8))) short short8;
typedef __attribute__((ext_vector_type(4))) float f32x4;

__device__ __forceinline__ float bf2f(unsigned int u) {
  union { unsigned int i; float f; } v; v.i = u << 16; return v.f;
}
__device__ __forceinline__ u16 f2bf(float f) {
  union { unsigned int i; float f; } v; v.f = f;
  unsigned int x = v.i;
  x += 0x7fffu + ((x >> 16) & 1u);   // RNE
  return (u16)(x >> 16);
}
__device__ __forceinline__ void split_bf(float x, u16& hi, u16& lo) {
  hi = f2bf(x);
  lo = f2bf(x - bf2f(hi));
}

__global__ void k_zero_i32(int* __restrict__ p, int n) {
  int i = blockIdx.x * blockDim.x + threadIdx.x;
  if (i < n) p[i] = 0;
}

__global__ void k_hist(const int* __restrict__ dst, int* __restrict__ deg, int e) {
  int i = blockIdx.x * blockDim.x + threadIdx.x;
  if (i < e) atomicAdd(&deg[dst[i]], 1);
}

// per-block partial sums of deg (int4-coalesced)
__global__ __launch_bounds__(256) void k_blocksum(const int* __restrict__ deg,
                                                  int* __restrict__ partials) {
  __shared__ int red[256];
  int tid = threadIdx.x;
  int t4 = blockIdx.x * 256 + tid;
  int sum = 0;
  if (t4 < NI4) {
    int4 v = ((const int4*)deg)[t4];
    sum = v.x + v.y + v.z + v.w;
  }
  red[tid] = sum;
  __syncthreads();
  for (int off = 128; off > 0; off >>= 1) {
    if (tid < off) red[tid] += red[tid + off];
    __syncthreads();
  }
  if (tid == 0) partials[blockIdx.x] = red[0];
}

// exclusive scan -> row_ptr; fused: dinv = rsqrt(deg+1), zero deg (cursor reuse)
__global__ __launch_bounds__(256) void k_scan2(int* __restrict__ deg,
                                               const int* __restrict__ partials,
                                               int* __restrict__ row_ptr,
                                               float* __restrict__ dinv) {
  __shared__ int sdata[256];
  __shared__ int sprefix;
  int tid = threadIdx.x, bid = blockIdx.x;
  int t4 = bid * 256 + tid;
  int4 v = make_int4(0, 0, 0, 0);
  if (t4 < NI4) v = ((const int4*)deg)[t4];
  int tsum = v.x + v.y + v.z + v.w;
  sdata[tid] = tsum;
  if (tid == 0) {
    int pre = 0;
    for (int b = 0; b < bid; ++b) pre += partials[b];
    sprefix = pre;
  }
  __syncthreads();
  for (int off = 1; off < 256; off <<= 1) {
    int val = (tid >= off) ? sdata[tid - off] : 0;
    __syncthreads();
    sdata[tid] += val;
    __syncthreads();
  }
  if (t4 < NI4) {
    int run = sdata[tid] - tsum + sprefix;
    int base = t4 * 4;
    float4 dv;
    dv.x = rsqrtf((float)v.x + 1.0f);
    dv.y = rsqrtf((float)v.y + 1.0f);
    dv.z = rsqrtf((float)v.z + 1.0f);
    dv.w = rsqrtf((float)v.w + 1.0f);
    *(float4*)(dinv + base) = dv;
    row_ptr[base + 0] = run; run += v.x;
    row_ptr[base + 1] = run; run += v.y;
    row_ptr[base + 2] = run; run += v.z;
    row_ptr[base + 3] = run; run += v.w;
    if (base + 4 == NNODES) row_ptr[NNODES] = run;
    ((int4*)deg)[t4] = make_int4(0, 0, 0, 0);  // reuse as cursor for k_fill
  }
}

__global__ void k_fill(const int* __restrict__ src, const int* __restrict__ dst,
                       const float* __restrict__ dinv, const int* __restrict__ row_ptr,
                       int* __restrict__ cursor, int* __restrict__ csr_src,
                       float* __restrict__ csr_nrm, int e) {
  int i = blockIdx.x * blockDim.x + threadIdx.x;
  if (i < e) {
    int d = dst[i], s = src[i];
    int pos = row_ptr[d] + atomicAdd(&cursor[d], 1);
    csr_src[pos] = s;
    csr_nrm[pos] = dinv[s] * dinv[d];
  }
}

// x [M,K] f32 -> hi/lo bf16 row-major
__global__ void k_split_x(const float* __restrict__ x, u16* __restrict__ hi,
                          u16* __restrict__ lo, int total4) {
  int i = blockIdx.x * blockDim.x + threadIdx.x;
  if (i >= total4) return;
  float4 v = *(const float4*)(x + (size_t)i * 4);
  ushort4 h, l;
  split_bf(v.x, h.x, l.x);
  split_bf(v.y, h.y, l.y);
  split_bf(v.z, h.z, l.z);
  split_bf(v.w, h.w, l.w);
  *(ushort4*)(hi + (size_t)i * 4) = h;
  *(ushort4*)(lo + (size_t)i * 4) = l;
}

// fused W1/W2/W3 split+swizzle into B-fragment order:
// frag (k-tile t, col-tile c): lane L holds B[k=t*32+(L>>4)*8+j][n=c*16+(L&15)]
// at ((t*16+c)*64 + L)*8 + j
__global__ void k_splitW3(const float* __restrict__ W1f, u16* __restrict__ W1h, u16* __restrict__ W1l,
                          const float* __restrict__ W2f, u16* __restrict__ W2h, u16* __restrict__ W2l,
                          const float* __restrict__ W3f, u16* __restrict__ W3h, u16* __restrict__ W3l) {
  int i = blockIdx.x * blockDim.x + threadIdx.x;
  const int s1 = DIN * 256, s2 = s1 + DHID * 256, s3 = s2 + DHID * 256;
  if (i >= s3) return;
  const float* W; u16 *hi, *lo; int li;
  if (i < s1)      { W = W1f; hi = W1h; lo = W1l; li = i; }
  else if (i < s2) { W = W2f; hi = W2h; lo = W2l; li = i - s1; }
  else             { W = W3f; hi = W3h; lo = W3l; li = i - s2; }
  int k = li >> 8, n = li & 255;
  int t = k >> 5, q = (k >> 3) & 3, j = k & 7;
  int c = n >> 4, m = n & 15;
  size_t pos = (((size_t)(t * 16 + c)) * 64 + q * 16 + m) * 8 + j;
  u16 h, l;
  split_bf(W[li], h, l);
  hi[pos] = h;
  lo[pos] = l;
}

// C[Mpad,256] = (Ahi+Alo) @ (Bhi+Blo), 3-pass split-bf16 MFMA.
// 1 wave = 32 rows (2 row-frags) x 256 cols; block = 4 waves = 128 rows. No LDS.
template<int K>
__global__ __launch_bounds__(256) void k_gemm_mfma(const u16* __restrict__ Ahi,
                                                   const u16* __restrict__ Alo,
                                                   const u16* __restrict__ Bhi,
                                                   const u16* __restrict__ Blo,
                                                   float* __restrict__ C) {
  const int lane = threadIdx.x & 63;
  const int wave = threadIdx.x >> 6;
  const int m0 = blockIdx.x * 128 + wave * 32;

  f32x4 acc0[16], acc1[16];
#pragma unroll
  for (int c = 0; c < 16; ++c) {
    acc0[c] = {0.f, 0.f, 0.f, 0.f};
    acc1[c] = {0.f, 0.f, 0.f, 0.f};
  }

  const u16* a0h = Ahi + (size_t)(m0 + (lane & 15)) * K + ((lane >> 4) * 8);
  const u16* a0l = Alo + (size_t)(m0 + (lane & 15)) * K + ((lane >> 4) * 8);
  const u16* a1h = a0h + (size_t)16 * K;
  const u16* a1l = a0l + (size_t)16 * K;

  for (int t = 0; t < K / 32; ++t) {
    short8 ah0 = *(const short8*)(a0h + t * 32);
    short8 al0 = *(const short8*)(a0l + t * 32);
    short8 ah1 = *(const short8*)(a1h + t * 32);
    short8 al1 = *(const short8*)(a1l + t * 32);
    const u16* bbase = Bhi + ((size_t)(t * 16) * 64 + lane) * 8;
    const u16* bbasel = Blo + ((size_t)(t * 16) * 64 + lane) * 8;
#pragma unroll
    for (int c = 0; c < 16; ++c) {
      short8 bh = *(const short8*)(bbase + (size_t)c * 512);
      short8 bl = *(const short8*)(bbasel + (size_t)c * 512);
      acc0[c] = __builtin_amdgcn_mfma_f32_16x16x32_bf16(ah0, bh, acc0[c], 0, 0, 0);
      acc0[c] = __builtin_amdgcn_mfma_f32_16x16x32_bf16(al0, bh, acc0[c], 0, 0, 0);
      acc0[c] = __builtin_amdgcn_mfma_f32_16x16x32_bf16(ah0, bl, acc0[c], 0, 0, 0);
      acc1[c] = __builtin_amdgcn_mfma_f32_16x16x32_bf16(ah1, bh, acc1[c], 0, 0, 0);
      acc1[c] = __builtin_amdgcn_mfma_f32_16x16x32_bf16(al1, bh, acc1[c], 0, 0, 0);
      acc1[c] = __builtin_amdgcn_mfma_f32_16x16x32_bf16(ah1, bl, acc1[c], 0, 0, 0);
    }
  }

  const int rbase = m0 + ((lane >> 4) * 4);
  const int cbase = lane & 15;
#pragma unroll
  for (int c = 0; c < 16; ++c) {
#pragma unroll
    for (int r = 0; r < 4; ++r) {
      C[(size_t)(rbase + r) * 256 + c * 16 + cbase] = acc0[c][r];
      C[(size_t)(rbase + 16 + r) * 256 + c * 16 + cbase] = acc1[c][r];
    }
  }
}

// one wave per node; 64 lanes x float4 = 256 channels; 4-deep gather pipeline
// MODE 0: relu + split-bf16 output (hhi/hlo); MODE 1: plain f32 output (final)
template<int MODE>
__global__ __launch_bounds__(256) void k_agg(const float* __restrict__ h,
                                             const float* __restrict__ dinv,
                                             const int* __restrict__ row_ptr,
                                             const int* __restrict__ csr_src,
                                             const float* __restrict__ csr_nrm,
                                             const float* __restrict__ bias,
                                             u16* __restrict__ hhi,
                                             u16* __restrict__ hlo,
                                             float* __restrict__ out, int n) {
  int node = blockIdx.x * 4 + (threadIdx.x >> 6);
  if (node >= n) return;
  int lane = threadIdx.x & 63;
  int c = lane * 4;
  float di = dinv[node];
  float s2 = di * di;
  float4 hv = *(const float4*)(h + (size_t)node * 256 + c);
  float4 bv = *(const float4*)(bias + c);
  float4 acc;
  acc.x = fmaf(s2, hv.x, bv.x);
  acc.y = fmaf(s2, hv.y, bv.y);
  acc.z = fmaf(s2, hv.z, bv.z);
  acc.w = fmaf(s2, hv.w, bv.w);
  int p = row_ptr[node], p1 = row_ptr[node + 1];
  for (; p + 4 <= p1; p += 4) {
    int s0 = csr_src[p], s1 = csr_src[p + 1], s2i = csr_src[p + 2], s3 = csr_src[p + 3];
    float w0 = csr_nrm[p], w1 = csr_nrm[p + 1], w2 = csr_nrm[p + 2], w3 = csr_nrm[p + 3];
    float4 v0 = *(const float4*)(h + (size_t)s0 * 256 + c);
    float4 v1 = *(const float4*)(h + (size_t)s1 * 256 + c);
    float4 v2 = *(const float4*)(h + (size_t)s2i * 256 + c);
    float4 v3 = *(const float4*)(h + (size_t)s3 * 256 + c);
    acc.x = fmaf(w0, v0.x, acc.x); acc.y = fmaf(w0, v0.y, acc.y);
    acc.z = fmaf(w0, v0.z, acc.z); acc.w = fmaf(w0, v0.w, acc.w);
    acc.x = fmaf(w1, v1.x, acc.x); acc.y = fmaf(w1, v1.y, acc.y);
    acc.z = fmaf(w1, v1.z, acc.z); acc.w = fmaf(w1, v1.w, acc.w);
    acc.x = fmaf(w2, v2.x, acc.x); acc.y = fmaf(w2, v2.y, acc.y);
    acc.z = fmaf(w2, v2.z, acc.z); acc.w = fmaf(w2, v2.w, acc.w);
    acc.x = fmaf(w3, v3.x, acc.x); acc.y = fmaf(w3, v3.y, acc.y);
    acc.z = fmaf(w3, v3.z, acc.z); acc.w = fmaf(w3, v3.w, acc.w);
  }
  for (; p < p1; ++p) {
    int s = csr_src[p];
    float w = csr_nrm[p];
    float4 v = *(const float4*)(h + (size_t)s * 256 + c);
    acc.x = fmaf(w, v.x, acc.x);
    acc.y = fmaf(w, v.y, acc.y);
    acc.z = fmaf(w, v.z, acc.z);
    acc.w = fmaf(w, v.w, acc.w);
  }
  if (MODE == 0) {
    acc.x = fmaxf(acc.x, 0.f); acc.y = fmaxf(acc.y, 0.f);
    acc.z = fmaxf(acc.z, 0.f); acc.w = fmaxf(acc.w, 0.f);
    ushort4 hq, lq;
    split_bf(acc.x, hq.x, lq.x);
    split_bf(acc.y, hq.y, lq.y);
    split_bf(acc.z, hq.z, lq.z);
    split_bf(acc.w, hq.w, lq.w);
    *(ushort4*)(hhi + (size_t)node * 256 + c) = hq;
    *(ushort4*)(hlo + (size_t)node * 256 + c) = lq;
  } else {
    *(float4*)(out + (size_t)node * 256 + c) = acc;
  }
}

extern "C" void kernel_launch(void* const* d_in, const int* in_sizes, int n_in,
                              void* d_out, int out_size, void* d_ws, size_t ws_size,
                              hipStream_t stream) {
  const float* x  = (const float*)d_in[0];
  const int*   ei = (const int*)d_in[1];
  const float* W1 = (const float*)d_in[2];
  const float* b1 = (const float*)d_in[3];
  const float* W2 = (const float*)d_in[4];
  const float* b2 = (const float*)d_in[5];
  const float* W3 = (const float*)d_in[6];
  const float* b3 = (const float*)d_in[7];
  float* out = (float*)d_out;
  (void)in_sizes; (void)n_in; (void)out_size; (void)ws_size;

  char* ws = (char*)d_ws;
  size_t off = 0;
  auto alloc = [&](size_t bytes) -> void* {
    void* p = (void*)(ws + off);
    off += (bytes + 255) & ~(size_t)255;
    return p;
  };
  float* dinv    = (float*)alloc((size_t)NNODES * 4);
  int*   deg     = (int*)alloc((size_t)NNODES * 4);
  int*   row_ptr = (int*)alloc((size_t)(NNODES + 1) * 4);
  int*   partials= (int*)alloc((size_t)NSB * 4);
  int*   csr_src = (int*)alloc((size_t)NEDGES * 4);
  float* csr_nrm = (float*)alloc((size_t)NEDGES * 4);
  float* bufA    = (float*)alloc((size_t)MPAD * 256 * 4);   // gemm out / agg in
  u16*   Hhi     = (u16*)alloc((size_t)MPAD * 256 * 2);     // also holds Xhi (K=128)
  u16*   Hlo     = (u16*)alloc((size_t)MPAD * 256 * 2);
  u16*   W1hi    = (u16*)alloc((size_t)DIN * 256 * 2);
  u16*   W1lo    = (u16*)alloc((size_t)DIN * 256 * 2);
  u16*   W2hi    = (u16*)alloc((size_t)DHID * 256 * 2);
  u16*   W2lo    = (u16*)alloc((size_t)DHID * 256 * 2);
  u16*   W3hi    = (u16*)alloc((size_t)DHID * 256 * 2);
  u16*   W3lo    = (u16*)alloc((size_t)DHID * 256 * 2);

  const int* e_src = ei;
  const int* e_dst = ei + NEDGES;

  const int tb = 256;
  k_zero_i32<<<(NNODES + tb - 1) / tb, tb, 0, stream>>>(deg, NNODES);
  k_hist<<<(NEDGES + tb - 1) / tb, tb, 0, stream>>>(e_dst, deg, NEDGES);
  k_blocksum<<<NSB, 256, 0, stream>>>(deg, partials);
  k_scan2<<<NSB, 256, 0, stream>>>(deg, partials, row_ptr, dinv);
  k_fill<<<(NEDGES + tb - 1) / tb, tb, 0, stream>>>(e_src, e_dst, dinv, row_ptr, deg,
                                                    csr_src, csr_nrm, NEDGES);

  int x4 = NNODES * DIN / 4;
  k_split_x<<<(x4 + tb - 1) / tb, tb, 0, stream>>>(x, Hhi, Hlo, x4);
  int wtot = (DIN + DHID + DHID) * 256;
  k_splitW3<<<(wtot + tb - 1) / tb, tb, 0, stream>>>(W1, W1hi, W1lo,
                                                     W2, W2hi, W2lo,
                                                     W3, W3hi, W3lo);

  const int gblocks = MPAD / 128;          // 391
  const int ablocks = (NNODES + 3) / 4;

  k_gemm_mfma<DIN><<<gblocks, 256, 0, stream>>>(Hhi, Hlo, W1hi, W1lo, bufA);
  k_agg<0><<<ablocks, 256, 0, stream>>>(bufA, dinv, row_ptr, csr_src, csr_nrm, b1,
                                        Hhi, Hlo, nullptr, NNODES);
  k_gemm_mfma<DHID><<<gblocks, 256, 0, stream>>>(Hhi, Hlo, W2hi, W2lo, bufA);
  k_agg<0><<<ablocks, 256, 0, stream>>>(bufA, dinv, row_ptr, csr_src, csr_nrm, b2,
                                        Hhi, Hlo, nullptr, NNODES);
  k_gemm_mfma<DHID><<<gblocks, 256, 0, stream>>>(Hhi, Hlo, W3hi, W3lo, bufA);
  k_agg<1><<<ablocks, 256, 0, stream>>>(bufA, dinv, row_ptr, csr_src, csr_nrm, b3,
                                        nullptr, nullptr, out, NNODES);
}

// Round 6
// 385.575 us; speedup vs baseline: 2.5094x; 1.3389x over previous
//
#include <hip/hip_runtime.h>

#define NNODES 50000
#define NEDGES 500000
#define DIN 128
#define DHID 256
#define MPAD 50048   // 391 blocks * 128 rows
#define NI4 12500
#define NSB 49

typedef unsigned short u16;
typedef __attribute__((ext_vector_type(8))) short short8;
typedef __attribute__((ext_vector_type(4))) float f32x4;

__device__ __forceinline__ float bf2f(unsigned int u) {
  union { unsigned int i; float f; } v; v.i = u << 16; return v.f;
}
__device__ __forceinline__ u16 f2bf(float f) {
  union { unsigned int i; float f; } v; v.f = f;
  unsigned int x = v.i;
  x += 0x7fffu + ((x >> 16) & 1u);   // RNE
  return (u16)(x >> 16);
}
__device__ __forceinline__ void split_bf(float x, u16& hi, u16& lo) {
  hi = f2bf(x);
  lo = f2bf(x - bf2f(hi));
}
__device__ __forceinline__ u16 f2h(float f) {
  union { _Float16 h; u16 u; } v; v.h = (_Float16)f; return v.u;
}
__device__ __forceinline__ float h2f(unsigned int u) {
  union { _Float16 h; u16 u; } v; v.u = (u16)u; return (float)v.h;
}

__global__ void k_zero_i32(int* __restrict__ p, int n) {
  int i = blockIdx.x * blockDim.x + threadIdx.x;
  if (i < n) p[i] = 0;
}

__global__ void k_hist(const int* __restrict__ dst, int* __restrict__ deg, int e) {
  int i = blockIdx.x * blockDim.x + threadIdx.x;
  if (i < e) atomicAdd(&deg[dst[i]], 1);
}

__global__ __launch_bounds__(256) void k_blocksum(const int* __restrict__ deg,
                                                  int* __restrict__ partials) {
  __shared__ int red[256];
  int tid = threadIdx.x;
  int t4 = blockIdx.x * 256 + tid;
  int sum = 0;
  if (t4 < NI4) {
    int4 v = ((const int4*)deg)[t4];
    sum = v.x + v.y + v.z + v.w;
  }
  red[tid] = sum;
  __syncthreads();
  for (int off = 128; off > 0; off >>= 1) {
    if (tid < off) red[tid] += red[tid + off];
    __syncthreads();
  }
  if (tid == 0) partials[blockIdx.x] = red[0];
}

// exclusive scan -> row_ptr; fused: dinv = rsqrt(deg+1), zero deg (cursor reuse)
__global__ __launch_bounds__(256) void k_scan2(int* __restrict__ deg,
                                               const int* __restrict__ partials,
                                               int* __restrict__ row_ptr,
                                               float* __restrict__ dinv) {
  __shared__ int sdata[256];
  __shared__ int sprefix;
  int tid = threadIdx.x, bid = blockIdx.x;
  int t4 = bid * 256 + tid;
  int4 v = make_int4(0, 0, 0, 0);
  if (t4 < NI4) v = ((const int4*)deg)[t4];
  int tsum = v.x + v.y + v.z + v.w;
  sdata[tid] = tsum;
  if (tid == 0) {
    int pre = 0;
    for (int b = 0; b < bid; ++b) pre += partials[b];
    sprefix = pre;
  }
  __syncthreads();
  for (int off = 1; off < 256; off <<= 1) {
    int val = (tid >= off) ? sdata[tid - off] : 0;
    __syncthreads();
    sdata[tid] += val;
    __syncthreads();
  }
  if (t4 < NI4) {
    int run = sdata[tid] - tsum + sprefix;
    int base = t4 * 4;
    float4 dv;
    dv.x = rsqrtf((float)v.x + 1.0f);
    dv.y = rsqrtf((float)v.y + 1.0f);
    dv.z = rsqrtf((float)v.z + 1.0f);
    dv.w = rsqrtf((float)v.w + 1.0f);
    *(float4*)(dinv + base) = dv;
    row_ptr[base + 0] = run; run += v.x;
    row_ptr[base + 1] = run; run += v.y;
    row_ptr[base + 2] = run; run += v.z;
    row_ptr[base + 3] = run; run += v.w;
    if (base + 4 == NNODES) row_ptr[NNODES] = run;
    ((int4*)deg)[t4] = make_int4(0, 0, 0, 0);
  }
}

__global__ void k_fill(const int* __restrict__ src, const int* __restrict__ dst,
                       const float* __restrict__ dinv, const int* __restrict__ row_ptr,
                       int* __restrict__ cursor, int* __restrict__ csr_src,
                       float* __restrict__ csr_nrm, int e) {
  int i = blockIdx.x * blockDim.x + threadIdx.x;
  if (i < e) {
    int d = dst[i], s = src[i];
    int pos = row_ptr[d] + atomicAdd(&cursor[d], 1);
    csr_src[pos] = s;
    csr_nrm[pos] = dinv[s] * dinv[d];
  }
}

// x f32 -> f16
__global__ void k_x2f16(const float* __restrict__ x, u16* __restrict__ xh, int total4) {
  int i = blockIdx.x * blockDim.x + threadIdx.x;
  if (i >= total4) return;
  float4 v = ((const float4*)x)[i];
  ushort4 o;
  o.x = f2h(v.x); o.y = f2h(v.y); o.z = f2h(v.z); o.w = f2h(v.w);
  ((ushort4*)xh)[i] = o;
}

// fused W1/W2/W3 split+swizzle into B-fragment order
__global__ void k_splitW3(const float* __restrict__ W1f, u16* __restrict__ W1h, u16* __restrict__ W1l,
                          const float* __restrict__ W2f, u16* __restrict__ W2h, u16* __restrict__ W2l,
                          const float* __restrict__ W3f, u16* __restrict__ W3h, u16* __restrict__ W3l) {
  int i = blockIdx.x * blockDim.x + threadIdx.x;
  const int s1 = DIN * 256, s2 = s1 + DHID * 256, s3 = s2 + DHID * 256;
  if (i >= s3) return;
  const float* W; u16 *hi, *lo; int li;
  if (i < s1)      { W = W1f; hi = W1h; lo = W1l; li = i; }
  else if (i < s2) { W = W2f; hi = W2h; lo = W2l; li = i - s1; }
  else             { W = W3f; hi = W3h; lo = W3l; li = i - s2; }
  int k = li >> 8, n = li & 255;
  int t = k >> 5, q = (k >> 3) & 3, j = k & 7;
  int c = n >> 4, m = n & 15;
  size_t pos = (((size_t)(t * 16 + c)) * 64 + q * 16 + m) * 8 + j;
  u16 h, l;
  split_bf(W[li], h, l);
  hi[pos] = h;
  lo[pos] = l;
}

// Aggregate-first gather: A[node] = dinv[node]^2 * h[node] + sum_e w_e * h[src_e]
// h is f16, width = 64*CPL. Output: split-bf16 (ahi/alo), row-major width cols.
template<int CPL>
__global__ __launch_bounds__(256) void k_aggF(const u16* __restrict__ hf,
                                              const float* __restrict__ dinv,
                                              const int* __restrict__ row_ptr,
                                              const int* __restrict__ csr_src,
                                              const float* __restrict__ csr_nrm,
                                              u16* __restrict__ ahi,
                                              u16* __restrict__ alo, int n) {
  const int W = 64 * CPL;
  int node = blockIdx.x * 4 + (threadIdx.x >> 6);
  if (node >= n) return;
  int lane = threadIdx.x & 63;
  int c = lane * CPL;

  float acc[CPL];
  float di = dinv[node];
  float s2 = di * di;

  auto ldh = [&](int row, float* v) {
    const u16* p = hf + (size_t)row * W + c;
    if constexpr (CPL == 2) {
      unsigned int u = *(const unsigned int*)p;
      v[0] = h2f(u & 0xffffu); v[1] = h2f(u >> 16);
    } else {
      uint2 u = *(const uint2*)p;
      v[0] = h2f(u.x & 0xffffu); v[1] = h2f(u.x >> 16);
      v[2] = h2f(u.y & 0xffffu); v[3] = h2f(u.y >> 16);
    }
  };

  {
    float v[CPL];
    ldh(node, v);
#pragma unroll
    for (int j = 0; j < CPL; ++j) acc[j] = s2 * v[j];
  }

  int p = row_ptr[node], p1 = row_ptr[node + 1];
  for (; p + 4 <= p1; p += 4) {
    int s0 = csr_src[p], s1 = csr_src[p + 1], s2i = csr_src[p + 2], s3 = csr_src[p + 3];
    float w0 = csr_nrm[p], w1 = csr_nrm[p + 1], w2 = csr_nrm[p + 2], w3 = csr_nrm[p + 3];
    float v0[CPL], v1[CPL], v2[CPL], v3[CPL];
    ldh(s0, v0); ldh(s1, v1); ldh(s2i, v2); ldh(s3, v3);
#pragma unroll
    for (int j = 0; j < CPL; ++j) {
      acc[j] = fmaf(w0, v0[j], acc[j]);
      acc[j] = fmaf(w1, v1[j], acc[j]);
      acc[j] = fmaf(w2, v2[j], acc[j]);
      acc[j] = fmaf(w3, v3[j], acc[j]);
    }
  }
  for (; p < p1; ++p) {
    int s = csr_src[p];
    float w = csr_nrm[p];
    float v[CPL];
    ldh(s, v);
#pragma unroll
    for (int j = 0; j < CPL; ++j) acc[j] = fmaf(w, v[j], acc[j]);
  }

  u16 hq[CPL], lq[CPL];
#pragma unroll
  for (int j = 0; j < CPL; ++j) split_bf(acc[j], hq[j], lq[j]);
  if constexpr (CPL == 2) {
    ushort2 h2v, l2v;
    h2v.x = hq[0]; h2v.y = hq[1];
    l2v.x = lq[0]; l2v.y = lq[1];
    *(ushort2*)(ahi + (size_t)node * W + c) = h2v;
    *(ushort2*)(alo + (size_t)node * W + c) = l2v;
  } else {
    ushort4 h4v, l4v;
    h4v.x = hq[0]; h4v.y = hq[1]; h4v.z = hq[2]; h4v.w = hq[3];
    l4v.x = lq[0]; l4v.y = lq[1]; l4v.z = lq[2]; l4v.w = lq[3];
    *(ushort4*)(ahi + (size_t)node * W + c) = h4v;
    *(ushort4*)(alo + (size_t)node * W + c) = l4v;
  }
}

// C = (Ahi+Alo) @ (Bhi+Blo) + bias, 3-pass split-bf16 MFMA.
// 1 wave = 32 rows x 256 cols; block = 4 waves = 128 rows. No LDS.
// EPI 0: relu + f16 store to hf16 (all MPAD rows). EPI 1: f32 store to outf, rows<NNODES.
template<int K, int EPI>
__global__ __launch_bounds__(256) void k_gemm_mfma(const u16* __restrict__ Ahi,
                                                   const u16* __restrict__ Alo,
                                                   const u16* __restrict__ Bhi,
                                                   const u16* __restrict__ Blo,
                                                   const float* __restrict__ bias,
                                                   u16* __restrict__ hf16,
                                                   float* __restrict__ outf) {
  const int lane = threadIdx.x & 63;
  const int wave = threadIdx.x >> 6;
  const int m0 = blockIdx.x * 128 + wave * 32;

  f32x4 acc0[16], acc1[16];
#pragma unroll
  for (int c = 0; c < 16; ++c) {
    acc0[c] = {0.f, 0.f, 0.f, 0.f};
    acc1[c] = {0.f, 0.f, 0.f, 0.f};
  }

  const u16* a0h = Ahi + (size_t)(m0 + (lane & 15)) * K + ((lane >> 4) * 8);
  const u16* a0l = Alo + (size_t)(m0 + (lane & 15)) * K + ((lane >> 4) * 8);
  const u16* a1h = a0h + (size_t)16 * K;
  const u16* a1l = a0l + (size_t)16 * K;

  for (int t = 0; t < K / 32; ++t) {
    short8 ah0 = *(const short8*)(a0h + t * 32);
    short8 al0 = *(const short8*)(a0l + t * 32);
    short8 ah1 = *(const short8*)(a1h + t * 32);
    short8 al1 = *(const short8*)(a1l + t * 32);
    const u16* bbase = Bhi + ((size_t)(t * 16) * 64 + lane) * 8;
    const u16* bbasel = Blo + ((size_t)(t * 16) * 64 + lane) * 8;
#pragma unroll
    for (int c = 0; c < 16; ++c) {
      short8 bh = *(const short8*)(bbase + (size_t)c * 512);
      short8 bl = *(const short8*)(bbasel + (size_t)c * 512);
      acc0[c] = __builtin_amdgcn_mfma_f32_16x16x32_bf16(ah0, bh, acc0[c], 0, 0, 0);
      acc0[c] = __builtin_amdgcn_mfma_f32_16x16x32_bf16(al0, bh, acc0[c], 0, 0, 0);
      acc0[c] = __builtin_amdgcn_mfma_f32_16x16x32_bf16(ah0, bl, acc0[c], 0, 0, 0);
      acc1[c] = __builtin_amdgcn_mfma_f32_16x16x32_bf16(ah1, bh, acc1[c], 0, 0, 0);
      acc1[c] = __builtin_amdgcn_mfma_f32_16x16x32_bf16(al1, bh, acc1[c], 0, 0, 0);
      acc1[c] = __builtin_amdgcn_mfma_f32_16x16x32_bf16(ah1, bl, acc1[c], 0, 0, 0);
    }
  }

  const int cbase = lane & 15;
  const int r0 = m0 + ((lane >> 4) * 4);
  float bv[16];
#pragma unroll
  for (int c = 0; c < 16; ++c) bv[c] = bias[c * 16 + cbase];

#pragma unroll
  for (int c = 0; c < 16; ++c) {
    int col = c * 16 + cbase;
#pragma unroll
    for (int r = 0; r < 4; ++r) {
      float v0 = acc0[c][r] + bv[c];
      float v1 = acc1[c][r] + bv[c];
      if (EPI == 0) {
        v0 = fmaxf(v0, 0.f);
        v1 = fmaxf(v1, 0.f);
        hf16[(size_t)(r0 + r) * 256 + col] = f2h(v0);
        hf16[(size_t)(r0 + 16 + r) * 256 + col] = f2h(v1);
      } else {
        if (r0 + r < NNODES) outf[(size_t)(r0 + r) * 256 + col] = v0;
        if (r0 + 16 + r < NNODES) outf[(size_t)(r0 + 16 + r) * 256 + col] = v1;
      }
    }
  }
}

extern "C" void kernel_launch(void* const* d_in, const int* in_sizes, int n_in,
                              void* d_out, int out_size, void* d_ws, size_t ws_size,
                              hipStream_t stream) {
  const float* x  = (const float*)d_in[0];
  const int*   ei = (const int*)d_in[1];
  const float* W1 = (const float*)d_in[2];
  const float* b1 = (const float*)d_in[3];
  const float* W2 = (const float*)d_in[4];
  const float* b2 = (const float*)d_in[5];
  const float* W3 = (const float*)d_in[6];
  const float* b3 = (const float*)d_in[7];
  float* out = (float*)d_out;
  (void)in_sizes; (void)n_in; (void)out_size; (void)ws_size;

  char* ws = (char*)d_ws;
  size_t off = 0;
  auto alloc = [&](size_t bytes) -> void* {
    void* p = (void*)(ws + off);
    off += (bytes + 255) & ~(size_t)255;
    return p;
  };
  float* dinv    = (float*)alloc((size_t)NNODES * 4);
  int*   deg     = (int*)alloc((size_t)NNODES * 4);
  int*   row_ptr = (int*)alloc((size_t)(NNODES + 1) * 4);
  int*   partials= (int*)alloc((size_t)NSB * 4);
  int*   csr_src = (int*)alloc((size_t)NEDGES * 4);
  float* csr_nrm = (float*)alloc((size_t)NEDGES * 4);
  u16*   xh      = (u16*)alloc((size_t)NNODES * DIN * 2);    // x as f16
  u16*   hbuf    = (u16*)alloc((size_t)MPAD * 256 * 2);      // h as f16 (gather target)
  u16*   A1hi    = (u16*)alloc((size_t)MPAD * DIN * 2);      // agg(x) split
  u16*   A1lo    = (u16*)alloc((size_t)MPAD * DIN * 2);
  u16*   A2hi    = (u16*)alloc((size_t)MPAD * 256 * 2);      // agg(h) split
  u16*   A2lo    = (u16*)alloc((size_t)MPAD * 256 * 2);
  u16*   W1hi    = (u16*)alloc((size_t)DIN * 256 * 2);
  u16*   W1lo    = (u16*)alloc((size_t)DIN * 256 * 2);
  u16*   W2hi    = (u16*)alloc((size_t)DHID * 256 * 2);
  u16*   W2lo    = (u16*)alloc((size_t)DHID * 256 * 2);
  u16*   W3hi    = (u16*)alloc((size_t)DHID * 256 * 2);
  u16*   W3lo    = (u16*)alloc((size_t)DHID * 256 * 2);

  const int* e_src = ei;
  const int* e_dst = ei + NEDGES;

  const int tb = 256;
  k_zero_i32<<<(NNODES + tb - 1) / tb, tb, 0, stream>>>(deg, NNODES);
  k_hist<<<(NEDGES + tb - 1) / tb, tb, 0, stream>>>(e_dst, deg, NEDGES);
  k_blocksum<<<NSB, 256, 0, stream>>>(deg, partials);
  k_scan2<<<NSB, 256, 0, stream>>>(deg, partials, row_ptr, dinv);
  k_fill<<<(NEDGES + tb - 1) / tb, tb, 0, stream>>>(e_src, e_dst, dinv, row_ptr, deg,
                                                    csr_src, csr_nrm, NEDGES);

  int x4 = NNODES * DIN / 4;
  k_x2f16<<<(x4 + tb - 1) / tb, tb, 0, stream>>>(x, xh, x4);
  int wtot = (DIN + DHID + DHID) * 256;
  k_splitW3<<<(wtot + tb - 1) / tb, tb, 0, stream>>>(W1, W1hi, W1lo,
                                                     W2, W2hi, W2lo,
                                                     W3, W3hi, W3lo);

  const int gblocks = MPAD / 128;          // 391
  const int ablocks = (NNODES + 3) / 4;

  // layer 1: agg(x) then GEMM(+b1+relu) -> h f16
  k_aggF<2><<<ablocks, 256, 0, stream>>>(xh, dinv, row_ptr, csr_src, csr_nrm,
                                         A1hi, A1lo, NNODES);
  k_gemm_mfma<DIN, 0><<<gblocks, 256, 0, stream>>>(A1hi, A1lo, W1hi, W1lo, b1,
                                                   hbuf, nullptr);
  // layer 2: agg(h1) then GEMM(+b2+relu) -> h f16
  k_aggF<4><<<ablocks, 256, 0, stream>>>(hbuf, dinv, row_ptr, csr_src, csr_nrm,
                                         A2hi, A2lo, NNODES);
  k_gemm_mfma<DHID, 0><<<gblocks, 256, 0, stream>>>(A2hi, A2lo, W2hi, W2lo, b2,
                                                    hbuf, nullptr);
  // layer 3: agg(h2) then GEMM(+b3) -> out f32
  k_aggF<4><<<ablocks, 256, 0, stream>>>(hbuf, dinv, row_ptr, csr_src, csr_nrm,
                                         A2hi, A2lo, NNODES);
  k_gemm_mfma<DHID, 1><<<gblocks, 256, 0, stream>>>(A2hi, A2lo, W3hi, W3lo, b3,
                                                    nullptr, out);
}